// Round 5
// baseline (655.807 us; speedup 1.0000x reference)
//
#include <hip/hip_runtime.h>
#include <stdint.h>

typedef __bf16 bf16x8 __attribute__((ext_vector_type(8)));
typedef float  f32x4  __attribute__((ext_vector_type(4)));
typedef float  fvec4  __attribute__((ext_vector_type(4)));
typedef float  f32x2  __attribute__((ext_vector_type(2)));

#define EDIM   16
#define HIDDEN 64
#define MDIM   16
#define NDIM   16
// Big GEMM: K' = 64 hid rows x 16 n = 32 chunks of 32; bias row handled
// by one extra register-sourced MFMA (A = h, B = b2 fragment).
#define KCHUNKS 32
#define NREP   8   // one output replica per XCD
#define WPB    8   // waves per block (512 threads)

// truncating f32->bf16 pack of two floats into one dword (x in low half).
__device__ __forceinline__ uint32_t pack_trunc(float x, float y) {
    return __builtin_amdgcn_perm(__builtin_bit_cast(uint32_t, x),
                                 __builtin_bit_cast(uint32_t, y),
                                 0x03020706u);
}

__device__ __forceinline__ uint16_t f32_to_bf16_rne(float f) {
    uint32_t u = __builtin_bit_cast(uint32_t, f);
    u += 0x7FFFu + ((u >> 16) & 1u);
    return (uint16_t)(u >> 16);
}

__device__ __forceinline__ bf16x8 u4_as_bf16x8(uint32_t a, uint32_t b,
                                               uint32_t c, uint32_t d) {
    union { uint32_t u[4]; bf16x8 v; } x;
    x.u[0] = a; x.u[1] = b; x.u[2] = c; x.u[3] = d;
    return x.v;
}

// packed f32 multiply: {a.x*b.x, a.y*b.y} in ONE VALU instruction (VOP3P).
__device__ __forceinline__ f32x2 pk_mul(f32x2 a, f32x2 b) {
    f32x2 d;
    asm("v_pk_mul_f32 %0, %1, %2" : "=v"(d) : "v"(a), "v"(b));
    return d;
}

// L2-local fp32 atomic add, saddr form: 32-bit byte voffset + SGPR base.
// No sc0/sc1 bits -> RMW executes in the issuing XCD's TCC and the line
// stays dirty-resident there (no fabric round-trip).
__device__ __forceinline__ void atomic_add_s(const float* base, uint32_t off,
                                             float v) {
    asm volatile("global_atomic_add_f32 %0, %1, %2"
                 :: "v"(off), "v"(v), "s"(base) : "memory");
}

// ---- prep: build B-fragment-ordered bf16 W2' table in global memory ----
// w2f[c][q][m][j] = bf16(W2[k=2c+(q>>1)][m*16 + (q&1)*8 + j]), 16384 ushorts.
__global__ void prep_w2frag(const float* __restrict__ W2,
                            ushort* __restrict__ w2f)
{
    int t = blockIdx.x * blockDim.x + threadIdx.x;
    if (t >= KCHUNKS * 512) return;
    int c = t >> 9, r = t & 511;
    int qq = r >> 7, m = (r >> 3) & 15, j = r & 7;
    int k = 2 * c + (qq >> 1);                     // 0..63
    int n = ((qq & 1) << 3) + j;
    w2f[t] = f32_to_bf16_rne(W2[k * 256 + m * 16 + n]);
}

// Per 16-edge tile (one wave):
//   hid-GEMM:  A = [e|1|0..] (16x32, K=32), B = W1ext (32x64) -> hid (16x64), relu
//   big GEMM:  A = U[e][kn] = hid_k*h_n (16x1024), B = W2' (1024x16) -> m (16x16)
//              + 1 bias MFMA: A = h (reg), B = b2-fragment (reg)
// W2' fragments read from GLOBAL memory (32 KB table, L1-resident per CU;
// streaming e/h/idx loads are non-temporal so they don't evict it). This
// removes 32 of 68 LDS ops/tile (the old per-tile 32KB sB re-read) and the
// 32KB sB buffer itself: LDS/block = 16KB -> occupancy cap 32 waves/CU.
// hid still round-trips through per-wave LDS (C-layout -> A-layout).
// Scatter: per-XCD replica (HW_REG_XCC_ID) + L2-local atomics; merge kernel
// sums the 8 replicas.
__global__ __launch_bounds__(512, 8) void msg_mfma_l1(
    const int*   __restrict__ idx,
    const float* __restrict__ h_w,
    const float* __restrict__ e_vw,
    const float* __restrict__ W1,    // [16][64]
    const float* __restrict__ b1,    // [64]
    const ushort* __restrict__ w2f,  // [KCHUNKS*512] fragment-ordered bf16 W2'
    const float* __restrict__ b2,    // [256]  ([m*16+n])
    float*       __restrict__ outb,  // [NREP][n_node*16] pre-zeroed
    int n_edge, int rep_stride)
{
    // per-wave hid transpose: sHid[w][k][e], k = 0..63
    __align__(16) __shared__ ushort sHid[WPB * 64 * 16];   // 16384 B

    const int tid = threadIdx.x;

    // ---- pick output replica (one per XCD) ----
    // s_getreg_b32 imm = ((size-1)<<11)|(offset<<6)|id ; HW_REG_XCC_ID = 20,
    // offset 0, size 4  ->  (3<<11)|20 = 6164.  Returns 0..7 on MI355X (m09).
    const int xcd = __builtin_amdgcn_s_getreg(6164) & (NREP - 1);
    const float* out = outb + (size_t)xcd * (size_t)rep_stride;

    const int lane = tid & 63;
    const int q    = lane >> 4;    // quad-row 0..3
    const int col  = lane & 15;
    const int w    = tid >> 6;     // wave in block (0..7)

    // ---- W1ext B-fragments in registers (once per wave) ----
    // frag[nt] element j = W1ext[k=q*8+j][nt*16+col]; row16 = b1, rows 17..31 = 0
    uint32_t w1u[4][4];
    #pragma unroll
    for (int nt = 0; nt < 4; nt++) {
        #pragma unroll
        for (int d = 0; d < 4; d++) w1u[nt][d] = 0;
        #pragma unroll
        for (int j = 0; j < 8; j++) {
            int k = q * 8 + j;
            float v = 0.f;
            if (k < 16)       v = W1[k * 64 + nt * 16 + col];
            else if (k == 16) v = b1[nt * 16 + col];
            w1u[nt][j >> 1] |= ((uint32_t)f32_to_bf16_rne(v)) << ((j & 1) * 16);
        }
    }

    // ---- b2 B-fragment in registers (bias MFMA, K-rows 64/65 of W2ext) ----
    // elem j = W2ext[64+(q>>1)][col*16 + (q&1)*8 + j]: q<2 -> b2, q>=2 -> 0.
    uint32_t b2u[4] = {0, 0, 0, 0};
    if (q < 2) {
        const float* bp = b2 + col * 16 + q * 8;
        #pragma unroll
        for (int j = 0; j < 8; j++)
            b2u[j >> 1] |= ((uint32_t)f32_to_bf16_rne(bp[j])) << ((j & 1) * 16);
    }

    bf16x8 w1f[4];
    #pragma unroll
    for (int nt = 0; nt < 4; nt++)
        w1f[nt] = u4_as_bf16x8(w1u[nt][0], w1u[nt][1], w1u[nt][2], w1u[nt][3]);
    const bf16x8 b2f = u4_as_bf16x8(b2u[0], b2u[1], b2u[2], b2u[3]);

    const int nhalf = (q & 1) << 3;  // which 8 of the 16 dims this quad holds
    const int ntile = (n_edge + 15) >> 4;
    const int wave_id = blockIdx.x * WPB + w;
    const int wstride = gridDim.x * WPB;
    if (wave_id >= ntile) return;

    const ushort* hidRd = &sHid[w * 1024 + (q >> 1) * 16 + col]; // + c*32
    ushort*       hidWr = &sHid[w * 1024 + col * 16 + q * 4];    // + nt*256
    // W2' fragment base for this lane: byte off = q*256 + col*16 (+ c*1024)
    const bf16x8* bRd = (const bf16x8*)w2f + (q * 16 + col);     // + c*64
    const uint32_t col4 = (uint32_t)col * 4u;

    // ---- prefetch first tile (non-temporal: pure streaming, zero reuse) ----
    int t = wave_id;
    fvec4 e0, e1, h0, h1; int4 nd; bool full;
    {
        int rbase = t * 16;
        full = (rbase + 16 <= n_edge);
        int row = full ? (rbase + col) : min(rbase + col, n_edge - 1);
        uint32_t ro = (uint32_t)row * 16u + (uint32_t)nhalf;
        const fvec4* ep = (const fvec4*)(e_vw + ro);
        e0 = __builtin_nontemporal_load(ep);
        e1 = __builtin_nontemporal_load(ep + 1);
        const fvec4* hp = (const fvec4*)(h_w + ro);
        h0 = __builtin_nontemporal_load(hp);
        h1 = __builtin_nontemporal_load(hp + 1);
        int r0 = rbase + q * 4;
        if (full) {
            nd.x = __builtin_nontemporal_load(idx + r0 + 0);
            nd.y = __builtin_nontemporal_load(idx + r0 + 1);
            nd.z = __builtin_nontemporal_load(idx + r0 + 2);
            nd.w = __builtin_nontemporal_load(idx + r0 + 3);
        } else {
            nd.x = __builtin_nontemporal_load(idx + min(r0 + 0, n_edge - 1));
            nd.y = __builtin_nontemporal_load(idx + min(r0 + 1, n_edge - 1));
            nd.z = __builtin_nontemporal_load(idx + min(r0 + 2, n_edge - 1));
            nd.w = __builtin_nontemporal_load(idx + min(r0 + 3, n_edge - 1));
        }
    }

    while (true) {
        // ---- issue next tile's loads BEFORE this tile's atomics ----
        int tn = t + wstride;
        bool have_next = (tn < ntile);
        fvec4 ne0, ne1, nh0, nh1; int4 nnd; bool nfull = false;
        if (have_next) {
            int rbase = tn * 16;
            nfull = (rbase + 16 <= n_edge);
            int row = nfull ? (rbase + col) : min(rbase + col, n_edge - 1);
            uint32_t ro = (uint32_t)row * 16u + (uint32_t)nhalf;
            const fvec4* ep = (const fvec4*)(e_vw + ro);
            ne0 = __builtin_nontemporal_load(ep);
            ne1 = __builtin_nontemporal_load(ep + 1);
            const fvec4* hp = (const fvec4*)(h_w + ro);
            nh0 = __builtin_nontemporal_load(hp);
            nh1 = __builtin_nontemporal_load(hp + 1);
            int r0 = rbase + q * 4;
            if (nfull) {
                nnd.x = __builtin_nontemporal_load(idx + r0 + 0);
                nnd.y = __builtin_nontemporal_load(idx + r0 + 1);
                nnd.z = __builtin_nontemporal_load(idx + r0 + 2);
                nnd.w = __builtin_nontemporal_load(idx + r0 + 3);
            } else {
                nnd.x = __builtin_nontemporal_load(idx + min(r0 + 0, n_edge - 1));
                nnd.y = __builtin_nontemporal_load(idx + min(r0 + 1, n_edge - 1));
                nnd.z = __builtin_nontemporal_load(idx + min(r0 + 2, n_edge - 1));
                nnd.w = __builtin_nontemporal_load(idx + min(r0 + 3, n_edge - 1));
            }
        }

        // ---- hid stage: 4 MFMAs, relu, pack, LDS transpose write ----
        uint32_t au0 = pack_trunc(e0.x, e0.y);
        uint32_t au1 = pack_trunc(e0.z, e0.w);
        uint32_t au2 = pack_trunc(e1.x, e1.y);
        uint32_t au3 = pack_trunc(e1.z, e1.w);
        if (q == 2) { au0 = 0x00003F80u; au1 = au2 = au3 = 0; } // bias row k=16 -> 1.0
        else if (q == 3) { au0 = au1 = au2 = au3 = 0; }
        bf16x8 av = u4_as_bf16x8(au0, au1, au2, au3);

        #pragma unroll
        for (int nt = 0; nt < 4; nt++) {
            f32x4 hc = {0.f, 0.f, 0.f, 0.f};
            hc = __builtin_amdgcn_mfma_f32_16x16x32_bf16(av, w1f[nt], hc, 0, 0, 0);
            // C layout: value = hid[e = q*4 + i][n = nt*16 + col]
            uint32_t lo = pack_trunc(fmaxf(hc[0], 0.f), fmaxf(hc[1], 0.f));
            uint32_t hi = pack_trunc(fmaxf(hc[2], 0.f), fmaxf(hc[3], 0.f));
            *(uint2*)(hidWr + nt * 256) = make_uint2(lo, hi);   // sHid[k=nt*16+col][e=q*4..+3]
        }

        // h as packed f32 pairs (loop-invariant within tile) for v_pk_mul_f32
        f32x2 hp0; hp0.x = h0.x; hp0.y = h0.y;
        f32x2 hp1; hp1.x = h0.z; hp1.y = h0.w;
        f32x2 hp2; hp2.x = h1.x; hp2.y = h1.y;
        f32x2 hp3; hp3.x = h1.z; hp3.y = h1.w;

        // ---- bias MFMA first: no dependency on the LDS hid round-trip.
        f32x4 acc = {0.f, 0.f, 0.f, 0.f};
        {
            uint32_t a0 = pack_trunc(hp0.x, hp0.y);
            uint32_t a1 = pack_trunc(hp1.x, hp1.y);
            uint32_t a2 = pack_trunc(hp2.x, hp2.y);
            uint32_t a3 = pack_trunc(hp3.x, hp3.y);
            bf16x8 af = u4_as_bf16x8(a0, a1, a2, a3);
            acc = __builtin_amdgcn_mfma_f32_16x16x32_bf16(af, b2f, acc, 0, 0, 0);
        }

        // ---- big GEMM: 32 chunks over kn; B-fragments from L1-resident
        // global table (vmem pipe), hid from per-wave LDS (lds pipe) ----
        #pragma unroll
        for (int c = 0; c < KCHUNKS; c++) {
            bf16x8 bfb = bRd[c * 64];                           // global b128, L1-hit
            uint32_t hku = ((uint32_t)hidRd[c * 32]) << 16;     // hid[k=2c+(q>>1)][e=col]
            float hkf = __builtin_bit_cast(float, hku);
            f32x2 hk2; hk2.x = hkf; hk2.y = hkf;
            f32x2 p0 = pk_mul(hk2, hp0);
            f32x2 p1 = pk_mul(hk2, hp1);
            f32x2 p2 = pk_mul(hk2, hp2);
            f32x2 p3 = pk_mul(hk2, hp3);
            uint32_t a0 = pack_trunc(p0.x, p0.y);
            uint32_t a1 = pack_trunc(p1.x, p1.y);
            uint32_t a2 = pack_trunc(p2.x, p2.y);
            uint32_t a3 = pack_trunc(p3.x, p3.y);
            bf16x8 af = u4_as_bf16x8(a0, a1, a2, a3);
            acc = __builtin_amdgcn_mfma_f32_16x16x32_bf16(af, bfb, acc, 0, 0, 0);
        }

        // ---- epilogue: C[row=e=q*4+i][col=m] -> L2-local atomics ----
        if (full) {
            atomic_add_s(out, (uint32_t)nd.x * 64u + col4, acc[0]);
            atomic_add_s(out, (uint32_t)nd.y * 64u + col4, acc[1]);
            atomic_add_s(out, (uint32_t)nd.z * 64u + col4, acc[2]);
            atomic_add_s(out, (uint32_t)nd.w * 64u + col4, acc[3]);
        } else {
            int r0 = t * 16 + q * 4;
            if (r0 + 0 < n_edge) atomic_add_s(out, (uint32_t)nd.x * 64u + col4, acc[0]);
            if (r0 + 1 < n_edge) atomic_add_s(out, (uint32_t)nd.y * 64u + col4, acc[1]);
            if (r0 + 2 < n_edge) atomic_add_s(out, (uint32_t)nd.z * 64u + col4, acc[2]);
            if (r0 + 3 < n_edge) atomic_add_s(out, (uint32_t)nd.w * 64u + col4, acc[3]);
        }

        if (!have_next) break;
        t = tn;
        e0 = ne0; e1 = ne1; h0 = nh0; h1 = nh1; nd = nnd; full = nfull;
    }
}

// ---- legacy fallback (ws too small): LDS-staged W2, device atomics ----
__global__ __launch_bounds__(512, 6) void msg_mfma_legacy(
    const int*   __restrict__ idx,
    const float* __restrict__ h_w,
    const float* __restrict__ e_vw,
    const float* __restrict__ W1,
    const float* __restrict__ b1,
    const float* __restrict__ W2,
    const float* __restrict__ b2,
    float*       __restrict__ out,
    int n_edge)
{
    __align__(16) __shared__ ushort sB[KCHUNKS * 512];
    __align__(16) __shared__ ushort sHid[WPB * 64 * 16];
    const int tid = threadIdx.x;
    for (int t = tid; t < KCHUNKS * 512; t += 512) {
        int c = t >> 9, r = t & 511;
        int qq = r >> 7, m = (r >> 3) & 15, j = r & 7;
        int k = 2 * c + (qq >> 1);
        int n = ((qq & 1) << 3) + j;
        sB[t] = f32_to_bf16_rne(W2[k * 256 + m * 16 + n]);
    }
    const int lane = tid & 63, q = lane >> 4, col = lane & 15, w = tid >> 6;
    uint32_t w1u[4][4];
    #pragma unroll
    for (int nt = 0; nt < 4; nt++) {
        #pragma unroll
        for (int d = 0; d < 4; d++) w1u[nt][d] = 0;
        #pragma unroll
        for (int j = 0; j < 8; j++) {
            int k = q * 8 + j;
            float v = 0.f;
            if (k < 16)       v = W1[k * 64 + nt * 16 + col];
            else if (k == 16) v = b1[nt * 16 + col];
            w1u[nt][j >> 1] |= ((uint32_t)f32_to_bf16_rne(v)) << ((j & 1) * 16);
        }
    }
    uint32_t b2u[4] = {0, 0, 0, 0};
    if (q < 2) {
        const float* bp = b2 + col * 16 + q * 8;
        #pragma unroll
        for (int j = 0; j < 8; j++)
            b2u[j >> 1] |= ((uint32_t)f32_to_bf16_rne(bp[j])) << ((j & 1) * 16);
    }
    __syncthreads();
    bf16x8 w1f[4];
    #pragma unroll
    for (int nt = 0; nt < 4; nt++)
        w1f[nt] = u4_as_bf16x8(w1u[nt][0], w1u[nt][1], w1u[nt][2], w1u[nt][3]);
    const bf16x8 b2f = u4_as_bf16x8(b2u[0], b2u[1], b2u[2], b2u[3]);
    const int nhalf = (q & 1) << 3;
    const int ntile = (n_edge + 15) >> 4;
    int t = blockIdx.x * WPB + w;
    const int wstride = gridDim.x * WPB;
    const ushort* hidRd = &sHid[w * 1024 + (q >> 1) * 16 + col];
    ushort*       hidWr = &sHid[w * 1024 + col * 16 + q * 4];
    const ushort* bRd   = &sB[q * 128 + col * 8];
    for (; t < ntile; t += wstride) {
        int row = min(t * 16 + col, n_edge - 1);
        const fvec4* ep = (const fvec4*)(e_vw + (size_t)row * 16 + nhalf);
        fvec4 e0 = ep[0], e1 = ep[1];
        const fvec4* hpp = (const fvec4*)(h_w + (size_t)row * 16 + nhalf);
        fvec4 h0 = hpp[0], h1 = hpp[1];
        int r0 = t * 16 + q * 4;
        int4 nd;
        nd.x = idx[min(r0 + 0, n_edge - 1)];
        nd.y = idx[min(r0 + 1, n_edge - 1)];
        nd.z = idx[min(r0 + 2, n_edge - 1)];
        nd.w = idx[min(r0 + 3, n_edge - 1)];
        uint32_t au0 = pack_trunc(e0.x, e0.y);
        uint32_t au1 = pack_trunc(e0.z, e0.w);
        uint32_t au2 = pack_trunc(e1.x, e1.y);
        uint32_t au3 = pack_trunc(e1.z, e1.w);
        if (q == 2) { au0 = 0x00003F80u; au1 = au2 = au3 = 0; }
        else if (q == 3) { au0 = au1 = au2 = au3 = 0; }
        bf16x8 av = u4_as_bf16x8(au0, au1, au2, au3);
        #pragma unroll
        for (int nt = 0; nt < 4; nt++) {
            f32x4 hc = {0.f, 0.f, 0.f, 0.f};
            hc = __builtin_amdgcn_mfma_f32_16x16x32_bf16(av, w1f[nt], hc, 0, 0, 0);
            uint32_t lo = pack_trunc(fmaxf(hc[0], 0.f), fmaxf(hc[1], 0.f));
            uint32_t hi = pack_trunc(fmaxf(hc[2], 0.f), fmaxf(hc[3], 0.f));
            *(uint2*)(hidWr + nt * 256) = make_uint2(lo, hi);
        }
        float hf[8] = {h0.x, h0.y, h0.z, h0.w, h1.x, h1.y, h1.z, h1.w};
        f32x4 acc = {0.f, 0.f, 0.f, 0.f};
        {
            uint32_t a0 = pack_trunc(hf[0], hf[1]);
            uint32_t a1 = pack_trunc(hf[2], hf[3]);
            uint32_t a2 = pack_trunc(hf[4], hf[5]);
            uint32_t a3 = pack_trunc(hf[6], hf[7]);
            acc = __builtin_amdgcn_mfma_f32_16x16x32_bf16(
                u4_as_bf16x8(a0, a1, a2, a3), b2f, acc, 0, 0, 0);
        }
        #pragma unroll
        for (int c = 0; c < KCHUNKS; c++) {
            uint32_t hku = ((uint32_t)hidRd[c * 32]) << 16;
            float hk = __builtin_bit_cast(float, hku);
            uint32_t a0 = pack_trunc(hk * hf[0], hk * hf[1]);
            uint32_t a1 = pack_trunc(hk * hf[2], hk * hf[3]);
            uint32_t a2 = pack_trunc(hk * hf[4], hk * hf[5]);
            uint32_t a3 = pack_trunc(hk * hf[6], hk * hf[7]);
            bf16x8 bfb = *(const bf16x8*)(bRd + c * 512);
            acc = __builtin_amdgcn_mfma_f32_16x16x32_bf16(
                u4_as_bf16x8(a0, a1, a2, a3), bfb, acc, 0, 0, 0);
        }
        if (r0 + 0 < n_edge) atomicAdd(out + (size_t)nd.x * 16 + col, acc[0]);
        if (r0 + 1 < n_edge) atomicAdd(out + (size_t)nd.y * 16 + col, acc[1]);
        if (r0 + 2 < n_edge) atomicAdd(out + (size_t)nd.z * 16 + col, acc[2]);
        if (r0 + 3 < n_edge) atomicAdd(out + (size_t)nd.w * 16 + col, acc[3]);
    }
}

// out[i] = sum over the 8 per-XCD replicas. 51.2MB read + 6.4MB write (~15us).
__global__ void merge_rep(const fvec4* __restrict__ rep,
                          fvec4* __restrict__ out, int n4, int stride4)
{
    int i = blockIdx.x * blockDim.x + threadIdx.x;
    if (i >= n4) return;
    fvec4 s = rep[i];
    #pragma unroll
    for (int r = 1; r < NREP; r++)
        s += rep[(size_t)r * stride4 + i];
    out[i] = s;
}

extern "C" void kernel_launch(void* const* d_in, const int* in_sizes, int n_in,
                              void* d_out, int out_size, void* d_ws, size_t ws_size,
                              hipStream_t stream) {
    const int*   idx  = (const int*)  d_in[0];
    const float* h_w  = (const float*)d_in[1];
    const float* e_vw = (const float*)d_in[2];
    const float* W1   = (const float*)d_in[4];
    const float* b1   = (const float*)d_in[5];
    const float* W2   = (const float*)d_in[6];
    const float* b2   = (const float*)d_in[7];
    float* out = (float*)d_out;
    const int n_edge = in_sizes[0];

    const size_t out_floats = (size_t)out_size;           // n_node * 16
    const size_t need_rep = (size_t)NREP * out_floats * sizeof(float);
    const size_t w2off = (need_rep + 255) & ~(size_t)255; // 256B-aligned
    const size_t need = w2off + (size_t)KCHUNKS * 512 * sizeof(ushort);

    if (ws_size >= need && (out_floats & 3) == 0) {
        float*  rep = (float*)d_ws;
        ushort* w2f = (ushort*)((char*)d_ws + w2off);
        hipMemsetAsync(rep, 0, need_rep, stream);
        prep_w2frag<<<32, 512, 0, stream>>>(W2, w2f);
        msg_mfma_l1<<<1024, 512, 0, stream>>>(idx, h_w, e_vw, W1, b1, w2f, b2,
                                              rep, n_edge, (int)out_floats);
        const int n4 = (int)(out_floats >> 2);
        const int mblocks = (n4 + 255) / 256;
        merge_rep<<<mblocks, 256, 0, stream>>>((const fvec4*)rep, (fvec4*)out,
                                               n4, n4);
    } else {
        hipMemsetAsync(out, 0, out_floats * sizeof(float), stream);
        msg_mfma_legacy<<<1536, 512, 0, stream>>>(idx, h_w, e_vw, W1, b1, W2,
                                                  b2, out, n_edge);
    }
}

// Round 6
// 320.580 us; speedup vs baseline: 2.0457x; 2.0457x over previous
//
#include <hip/hip_runtime.h>
#include <stdint.h>

typedef __bf16 bf16x8 __attribute__((ext_vector_type(8)));
typedef float  f32x4  __attribute__((ext_vector_type(4)));
typedef float  fvec4  __attribute__((ext_vector_type(4)));
typedef float  f32x2  __attribute__((ext_vector_type(2)));

#define EDIM   16
#define HIDDEN 64
#define MDIM   16
#define NDIM   16
// Big GEMM: K' = 64 hid rows x 16 n = 32 chunks of 32; bias row handled
// by one extra register-sourced MFMA per edge-group (A = h, B = b2 frag).
#define KCHUNKS 32
#define NREP   8   // one output replica per XCD
#define WPB    8   // waves per block (512 threads)

// truncating f32->bf16 pack of two floats into one dword (x in low half).
__device__ __forceinline__ uint32_t pack_trunc(float x, float y) {
    return __builtin_amdgcn_perm(__builtin_bit_cast(uint32_t, x),
                                 __builtin_bit_cast(uint32_t, y),
                                 0x03020706u);
}

__device__ __forceinline__ uint16_t f32_to_bf16_rne(float f) {
    uint32_t u = __builtin_bit_cast(uint32_t, f);
    u += 0x7FFFu + ((u >> 16) & 1u);
    return (uint16_t)(u >> 16);
}

__device__ __forceinline__ bf16x8 u4_as_bf16x8(uint32_t a, uint32_t b,
                                               uint32_t c, uint32_t d) {
    union { uint32_t u[4]; bf16x8 v; } x;
    x.u[0] = a; x.u[1] = b; x.u[2] = c; x.u[3] = d;
    return x.v;
}

// packed f32 multiply: {a.x*b.x, a.y*b.y} in ONE VALU instruction (VOP3P).
__device__ __forceinline__ f32x2 pk_mul(f32x2 a, f32x2 b) {
    f32x2 d;
    asm("v_pk_mul_f32 %0, %1, %2" : "=v"(d) : "v"(a), "v"(b));
    return d;
}

// L2-local fp32 atomic add, saddr form: 32-bit byte voffset + SGPR base.
// No sc0/sc1 bits -> RMW executes in the issuing XCD's TCC and the line
// stays dirty-resident there (no fabric round-trip).
__device__ __forceinline__ void atomic_add_s(const float* base, uint32_t off,
                                             float v) {
    asm volatile("global_atomic_add_f32 %0, %1, %2"
                 :: "v"(off), "v"(v), "s"(base) : "memory");
}

__device__ __forceinline__ void load_eh(const float* p, uint32_t ro,
                                        fvec4& a, fvec4& b) {
    const fvec4* pp = (const fvec4*)(p + ro);
    a = __builtin_nontemporal_load(pp);
    b = __builtin_nontemporal_load(pp + 1);
}

__device__ __forceinline__ int4 load_idx4(const int* __restrict__ idx,
                                          int r, int n_edge, bool full) {
    int4 v;
    if (full) {
        v.x = __builtin_nontemporal_load(idx + r + 0);
        v.y = __builtin_nontemporal_load(idx + r + 1);
        v.z = __builtin_nontemporal_load(idx + r + 2);
        v.w = __builtin_nontemporal_load(idx + r + 3);
    } else {
        v.x = __builtin_nontemporal_load(idx + min(r + 0, n_edge - 1));
        v.y = __builtin_nontemporal_load(idx + min(r + 1, n_edge - 1));
        v.z = __builtin_nontemporal_load(idx + min(r + 2, n_edge - 1));
        v.w = __builtin_nontemporal_load(idx + min(r + 3, n_edge - 1));
    }
    return v;
}

// hid stage for one 16-edge group: 4 MFMAs, relu, pack, LDS transpose write.
__device__ __forceinline__ void hid_stage(fvec4 ea, fvec4 eb, int q,
                                          const bf16x8* w1f, ushort* hidWr) {
    uint32_t au0 = pack_trunc(ea.x, ea.y);
    uint32_t au1 = pack_trunc(ea.z, ea.w);
    uint32_t au2 = pack_trunc(eb.x, eb.y);
    uint32_t au3 = pack_trunc(eb.z, eb.w);
    if (q == 2) { au0 = 0x00003F80u; au1 = au2 = au3 = 0; } // bias row k=16 -> 1.0
    else if (q == 3) { au0 = au1 = au2 = au3 = 0; }
    bf16x8 av = u4_as_bf16x8(au0, au1, au2, au3);
    #pragma unroll
    for (int nt = 0; nt < 4; nt++) {
        f32x4 hc = {0.f, 0.f, 0.f, 0.f};
        hc = __builtin_amdgcn_mfma_f32_16x16x32_bf16(av, w1f[nt], hc, 0, 0, 0);
        // C layout: value = hid[e = q*4 + i][n = nt*16 + col]
        uint32_t lo = pack_trunc(fmaxf(hc[0], 0.f), fmaxf(hc[1], 0.f));
        uint32_t hi = pack_trunc(fmaxf(hc[2], 0.f), fmaxf(hc[3], 0.f));
        *(uint2*)(hidWr + nt * 256) = make_uint2(lo, hi); // sHid[k=nt*16+col][e=q*4..+3]
    }
}

// Per 32-edge tile (one wave, TWO 16-edge groups sharing each B-fragment):
//   hid-GEMM x2: A = [e|1|0..] (16x32), B = W1ext (32x64) -> hid, relu
//   big GEMM:  per chunk c: ONE ds_read_b128 of W2' feeds TWO MFMAs
//              (group0 and group1 A-frags) -> sB traffic per edge HALVED.
//   + 2 bias MFMAs (A = h, B = b2 fragment, register-sourced).
// LDS = 32KB sB + 32KB sHid (2 groups x 8 waves) = 64KB -> 2 blocks/CU.
// Scatter: per-XCD replica (HW_REG_XCC_ID) + L2-local atomics; merge kernel
// sums the 8 replicas. In-place next-tile prefetch (e after hid stage,
// h after chunk loop, nd double-buffered) keeps all loads issued BEFORE
// this tile's atomics so vmcnt never waits on atomic retirement.
__global__ __launch_bounds__(512, 4) void msg_mfma32(
    const int*   __restrict__ idx,
    const float* __restrict__ h_w,
    const float* __restrict__ e_vw,
    const float* __restrict__ W1,   // [16][64]
    const float* __restrict__ b1,   // [64]
    const float* __restrict__ W2,   // [64][256]  ([k][m*16+n])
    const float* __restrict__ b2,   // [256]      ([m*16+n])
    float*       __restrict__ outb, // [NREP][n_node*16] pre-zeroed
    int n_edge, int rep_stride)
{
    // B-fragment-ordered W2: sB[c][q][m][j] = W2[k=2c+(q>>1)][m*16 + (q&1)*8+j]
    __align__(16) __shared__ ushort sB[KCHUNKS * 512];       // 32768 B
    // per-wave-per-group hid transpose: sHid[(w*2+g)][k][e], k = 0..63
    __align__(16) __shared__ ushort sHid[WPB * 2 * 1024];    // 32768 B

    const int tid = threadIdx.x;

    // ---- pick output replica (one per XCD) ----
    // s_getreg_b32 imm = ((size-1)<<11)|(offset<<6)|id ; HW_REG_XCC_ID = 20,
    // offset 0, size 4  ->  (3<<11)|20 = 6164.  Returns 0..7 on MI355X (m09).
    const int xcd = __builtin_amdgcn_s_getreg(6164) & (NREP - 1);
    const float* out = outb + (size_t)xcd * (size_t)rep_stride;

    // ---- stage W2 fragments (once per block) ----
    for (int t = tid; t < KCHUNKS * 512; t += 512) {
        int c = t >> 9, r = t & 511;
        int qq = r >> 7, m = (r >> 3) & 15, j = r & 7;
        int k = 2 * c + (qq >> 1);                     // 0..63
        int n = ((qq & 1) << 3) + j;
        sB[t] = f32_to_bf16_rne(W2[k * 256 + m * 16 + n]);
    }

    const int lane = tid & 63;
    const int q    = lane >> 4;    // quad-row 0..3
    const int col  = lane & 15;
    const int w    = tid >> 6;     // wave in block (0..7)

    // ---- W1ext B-fragments in registers (once per wave) ----
    uint32_t w1u[4][4];
    #pragma unroll
    for (int nt = 0; nt < 4; nt++) {
        #pragma unroll
        for (int d = 0; d < 4; d++) w1u[nt][d] = 0;
        #pragma unroll
        for (int j = 0; j < 8; j++) {
            int k = q * 8 + j;
            float v = 0.f;
            if (k < 16)       v = W1[k * 64 + nt * 16 + col];
            else if (k == 16) v = b1[nt * 16 + col];
            w1u[nt][j >> 1] |= ((uint32_t)f32_to_bf16_rne(v)) << ((j & 1) * 16);
        }
    }

    // ---- b2 B-fragment (bias MFMA): q<2 -> b2, q>=2 -> 0 ----
    uint32_t b2u[4] = {0, 0, 0, 0};
    if (q < 2) {
        const float* bp = b2 + col * 16 + q * 8;
        #pragma unroll
        for (int j = 0; j < 8; j++)
            b2u[j >> 1] |= ((uint32_t)f32_to_bf16_rne(bp[j])) << ((j & 1) * 16);
    }
    __syncthreads();

    bf16x8 w1f[4];
    #pragma unroll
    for (int nt = 0; nt < 4; nt++)
        w1f[nt] = u4_as_bf16x8(w1u[nt][0], w1u[nt][1], w1u[nt][2], w1u[nt][3]);
    const bf16x8 b2f = u4_as_bf16x8(b2u[0], b2u[1], b2u[2], b2u[3]);

    const int nhalf = (q & 1) << 3;  // which 8 of the 16 dims this quad holds
    const int ntile = (n_edge + 31) >> 5;       // 32 edges per tile
    const int wave_id = blockIdx.x * WPB + w;
    const int wstride = gridDim.x * WPB;
    if (wave_id >= ntile) return;

    const ushort* hidRd0 = &sHid[(w * 2 + 0) * 1024 + (q >> 1) * 16 + col];
    const ushort* hidRd1 = hidRd0 + 1024;
    ushort*       hidWr0 = &sHid[(w * 2 + 0) * 1024 + col * 16 + q * 4];
    ushort*       hidWr1 = hidWr0 + 1024;
    const ushort* bRd    = &sB[q * 128 + col * 8];            // + c*512
    const uint32_t col4  = (uint32_t)col * 4u;

    // ---- initial tile load ----
    int t = wave_id;
    fvec4 e0, e1, e2, e3, h0, h1, h2, h3; int4 nd0, nd1; bool full;
    {
        int rbase = t * 32;
        full = (rbase + 32 <= n_edge);
        int row0 = full ? (rbase + col)      : min(rbase + col,      n_edge - 1);
        int row1 = full ? (rbase + 16 + col) : min(rbase + 16 + col, n_edge - 1);
        uint32_t ro0 = (uint32_t)row0 * 16u + (uint32_t)nhalf;
        uint32_t ro1 = (uint32_t)row1 * 16u + (uint32_t)nhalf;
        load_eh(e_vw, ro0, e0, e1);
        load_eh(e_vw, ro1, e2, e3);
        load_eh(h_w,  ro0, h0, h1);
        load_eh(h_w,  ro1, h2, h3);
        nd0 = load_idx4(idx, rbase + q * 4,      n_edge, full);
        nd1 = load_idx4(idx, rbase + 16 + q * 4, n_edge, full);
    }

    while (true) {
        int tn = t + wstride;
        bool have_next = (tn < ntile);

        // ---- hid stage: both groups (consumes e0..e3) ----
        hid_stage(e0, e1, q, w1f, hidWr0);
        hid_stage(e2, e3, q, w1f, hidWr1);

        // ---- e-prefetch next tile, in place (e dead after hid stage);
        //      issues BEFORE this tile's atomics ----
        bool nfull = false;
        if (have_next) {
            int rbase = tn * 32;
            nfull = (rbase + 32 <= n_edge);
            int row0 = nfull ? (rbase + col)      : min(rbase + col,      n_edge - 1);
            int row1 = nfull ? (rbase + 16 + col) : min(rbase + 16 + col, n_edge - 1);
            load_eh(e_vw, (uint32_t)row0 * 16u + (uint32_t)nhalf, e0, e1);
            load_eh(e_vw, (uint32_t)row1 * 16u + (uint32_t)nhalf, e2, e3);
        }

        // h as packed f32 pairs for v_pk_mul_f32
        f32x2 hp0; hp0.x = h0.x; hp0.y = h0.y;
        f32x2 hp1; hp1.x = h0.z; hp1.y = h0.w;
        f32x2 hp2; hp2.x = h1.x; hp2.y = h1.y;
        f32x2 hp3; hp3.x = h1.z; hp3.y = h1.w;
        f32x2 hq0; hq0.x = h2.x; hq0.y = h2.y;
        f32x2 hq1; hq1.x = h2.z; hq1.y = h2.w;
        f32x2 hq2; hq2.x = h3.x; hq2.y = h3.y;
        f32x2 hq3; hq3.x = h3.z; hq3.y = h3.w;

        // ---- bias MFMAs (no dependency on the LDS hid round-trip) ----
        f32x4 acc0 = {0.f, 0.f, 0.f, 0.f};
        f32x4 acc1 = {0.f, 0.f, 0.f, 0.f};
        {
            bf16x8 af0 = u4_as_bf16x8(pack_trunc(hp0.x, hp0.y), pack_trunc(hp1.x, hp1.y),
                                      pack_trunc(hp2.x, hp2.y), pack_trunc(hp3.x, hp3.y));
            acc0 = __builtin_amdgcn_mfma_f32_16x16x32_bf16(af0, b2f, acc0, 0, 0, 0);
            bf16x8 af1 = u4_as_bf16x8(pack_trunc(hq0.x, hq0.y), pack_trunc(hq1.x, hq1.y),
                                      pack_trunc(hq2.x, hq2.y), pack_trunc(hq3.x, hq3.y));
            acc1 = __builtin_amdgcn_mfma_f32_16x16x32_bf16(af1, b2f, acc1, 0, 0, 0);
        }

        // ---- big GEMM: 32 chunks; ONE b128 B-read feeds TWO MFMAs ----
        #pragma unroll
        for (int c = 0; c < KCHUNKS; c++) {
            bf16x8 bfb = *(const bf16x8*)(bRd + c * 512);       // ds_read_b128
            // group 0
            {
                uint32_t hku = ((uint32_t)hidRd0[c * 32]) << 16;
                float hkf = __builtin_bit_cast(float, hku);
                f32x2 hk2; hk2.x = hkf; hk2.y = hkf;
                f32x2 p0 = pk_mul(hk2, hp0);
                f32x2 p1 = pk_mul(hk2, hp1);
                f32x2 p2 = pk_mul(hk2, hp2);
                f32x2 p3 = pk_mul(hk2, hp3);
                bf16x8 af = u4_as_bf16x8(pack_trunc(p0.x, p0.y), pack_trunc(p1.x, p1.y),
                                         pack_trunc(p2.x, p2.y), pack_trunc(p3.x, p3.y));
                acc0 = __builtin_amdgcn_mfma_f32_16x16x32_bf16(af, bfb, acc0, 0, 0, 0);
            }
            // group 1 (reuses bfb)
            {
                uint32_t hku = ((uint32_t)hidRd1[c * 32]) << 16;
                float hkf = __builtin_bit_cast(float, hku);
                f32x2 hk2; hk2.x = hkf; hk2.y = hkf;
                f32x2 p0 = pk_mul(hk2, hq0);
                f32x2 p1 = pk_mul(hk2, hq1);
                f32x2 p2 = pk_mul(hk2, hq2);
                f32x2 p3 = pk_mul(hk2, hq3);
                bf16x8 af = u4_as_bf16x8(pack_trunc(p0.x, p0.y), pack_trunc(p1.x, p1.y),
                                         pack_trunc(p2.x, p2.y), pack_trunc(p3.x, p3.y));
                acc1 = __builtin_amdgcn_mfma_f32_16x16x32_bf16(af, bfb, acc1, 0, 0, 0);
            }
        }

        // ---- h + nd prefetch next (h in place: dead after chunk loop);
        //      still issues BEFORE this tile's atomics ----
        int4 ndn0, ndn1;
        if (have_next) {
            int rbase = tn * 32;
            int row0 = nfull ? (rbase + col)      : min(rbase + col,      n_edge - 1);
            int row1 = nfull ? (rbase + 16 + col) : min(rbase + 16 + col, n_edge - 1);
            load_eh(h_w, (uint32_t)row0 * 16u + (uint32_t)nhalf, h0, h1);
            load_eh(h_w, (uint32_t)row1 * 16u + (uint32_t)nhalf, h2, h3);
            ndn0 = load_idx4(idx, rbase + q * 4,      n_edge, nfull);
            ndn1 = load_idx4(idx, rbase + 16 + q * 4, n_edge, nfull);
        }

        // ---- epilogue: L2-local atomics (replica is single-XCD-writer) ----
        if (full) {
            atomic_add_s(out, (uint32_t)nd0.x * 64u + col4, acc0[0]);
            atomic_add_s(out, (uint32_t)nd0.y * 64u + col4, acc0[1]);
            atomic_add_s(out, (uint32_t)nd0.z * 64u + col4, acc0[2]);
            atomic_add_s(out, (uint32_t)nd0.w * 64u + col4, acc0[3]);
            atomic_add_s(out, (uint32_t)nd1.x * 64u + col4, acc1[0]);
            atomic_add_s(out, (uint32_t)nd1.y * 64u + col4, acc1[1]);
            atomic_add_s(out, (uint32_t)nd1.z * 64u + col4, acc1[2]);
            atomic_add_s(out, (uint32_t)nd1.w * 64u + col4, acc1[3]);
        } else {
            int r0 = t * 32 + q * 4;
            int r1 = r0 + 16;
            if (r0 + 0 < n_edge) atomic_add_s(out, (uint32_t)nd0.x * 64u + col4, acc0[0]);
            if (r0 + 1 < n_edge) atomic_add_s(out, (uint32_t)nd0.y * 64u + col4, acc0[1]);
            if (r0 + 2 < n_edge) atomic_add_s(out, (uint32_t)nd0.z * 64u + col4, acc0[2]);
            if (r0 + 3 < n_edge) atomic_add_s(out, (uint32_t)nd0.w * 64u + col4, acc0[3]);
            if (r1 + 0 < n_edge) atomic_add_s(out, (uint32_t)nd1.x * 64u + col4, acc1[0]);
            if (r1 + 1 < n_edge) atomic_add_s(out, (uint32_t)nd1.y * 64u + col4, acc1[1]);
            if (r1 + 2 < n_edge) atomic_add_s(out, (uint32_t)nd1.z * 64u + col4, acc1[2]);
            if (r1 + 3 < n_edge) atomic_add_s(out, (uint32_t)nd1.w * 64u + col4, acc1[3]);
        }

        if (!have_next) break;
        t = tn; full = nfull; nd0 = ndn0; nd1 = ndn1;
    }
}

// ---- legacy fallback (ws too small): round-4 16-edge kernel, device atomics ----
__global__ __launch_bounds__(512, 6) void msg_mfma_legacy(
    const int*   __restrict__ idx,
    const float* __restrict__ h_w,
    const float* __restrict__ e_vw,
    const float* __restrict__ W1,
    const float* __restrict__ b1,
    const float* __restrict__ W2,
    const float* __restrict__ b2,
    float*       __restrict__ out,
    int n_edge)
{
    __align__(16) __shared__ ushort sB[KCHUNKS * 512];
    __align__(16) __shared__ ushort sHid[WPB * 64 * 16];
    const int tid = threadIdx.x;
    for (int t = tid; t < KCHUNKS * 512; t += 512) {
        int c = t >> 9, r = t & 511;
        int qq = r >> 7, m = (r >> 3) & 15, j = r & 7;
        int k = 2 * c + (qq >> 1);
        int n = ((qq & 1) << 3) + j;
        sB[t] = f32_to_bf16_rne(W2[k * 256 + m * 16 + n]);
    }
    const int lane = tid & 63, q = lane >> 4, col = lane & 15, w = tid >> 6;
    uint32_t w1u[4][4];
    #pragma unroll
    for (int nt = 0; nt < 4; nt++) {
        #pragma unroll
        for (int d = 0; d < 4; d++) w1u[nt][d] = 0;
        #pragma unroll
        for (int j = 0; j < 8; j++) {
            int k = q * 8 + j;
            float v = 0.f;
            if (k < 16)       v = W1[k * 64 + nt * 16 + col];
            else if (k == 16) v = b1[nt * 16 + col];
            w1u[nt][j >> 1] |= ((uint32_t)f32_to_bf16_rne(v)) << ((j & 1) * 16);
        }
    }
    uint32_t b2u[4] = {0, 0, 0, 0};
    if (q < 2) {
        const float* bp = b2 + col * 16 + q * 8;
        #pragma unroll
        for (int j = 0; j < 8; j++)
            b2u[j >> 1] |= ((uint32_t)f32_to_bf16_rne(bp[j])) << ((j & 1) * 16);
    }
    __syncthreads();
    bf16x8 w1f[4];
    #pragma unroll
    for (int nt = 0; nt < 4; nt++)
        w1f[nt] = u4_as_bf16x8(w1u[nt][0], w1u[nt][1], w1u[nt][2], w1u[nt][3]);
    const bf16x8 b2f = u4_as_bf16x8(b2u[0], b2u[1], b2u[2], b2u[3]);
    const int nhalf = (q & 1) << 3;
    const int ntile = (n_edge + 15) >> 4;
    int t = blockIdx.x * WPB + w;
    const int wstride = gridDim.x * WPB;
    const ushort* hidRd = &sHid[w * 1024 + (q >> 1) * 16 + col];
    ushort*       hidWr = &sHid[w * 1024 + col * 16 + q * 4];
    const ushort* bRd   = &sB[q * 128 + col * 8];
    for (; t < ntile; t += wstride) {
        int row = min(t * 16 + col, n_edge - 1);
        const fvec4* ep = (const fvec4*)(e_vw + (size_t)row * 16 + nhalf);
        fvec4 e0 = ep[0], e1 = ep[1];
        const fvec4* hpp = (const fvec4*)(h_w + (size_t)row * 16 + nhalf);
        fvec4 h0 = hpp[0], h1 = hpp[1];
        int r0 = t * 16 + q * 4;
        int4 nd;
        nd.x = idx[min(r0 + 0, n_edge - 1)];
        nd.y = idx[min(r0 + 1, n_edge - 1)];
        nd.z = idx[min(r0 + 2, n_edge - 1)];
        nd.w = idx[min(r0 + 3, n_edge - 1)];
        hid_stage(e0, e1, q, w1f, hidWr);
        float hf[8] = {h0.x, h0.y, h0.z, h0.w, h1.x, h1.y, h1.z, h1.w};
        f32x4 acc = {0.f, 0.f, 0.f, 0.f};
        {
            uint32_t a0 = pack_trunc(hf[0], hf[1]);
            uint32_t a1 = pack_trunc(hf[2], hf[3]);
            uint32_t a2 = pack_trunc(hf[4], hf[5]);
            uint32_t a3 = pack_trunc(hf[6], hf[7]);
            acc = __builtin_amdgcn_mfma_f32_16x16x32_bf16(
                u4_as_bf16x8(a0, a1, a2, a3), b2f, acc, 0, 0, 0);
        }
        #pragma unroll
        for (int c = 0; c < KCHUNKS; c++) {
            uint32_t hku = ((uint32_t)hidRd[c * 32]) << 16;
            float hk = __builtin_bit_cast(float, hku);
            uint32_t a0 = pack_trunc(hk * hf[0], hk * hf[1]);
            uint32_t a1 = pack_trunc(hk * hf[2], hk * hf[3]);
            uint32_t a2 = pack_trunc(hk * hf[4], hk * hf[5]);
            uint32_t a3 = pack_trunc(hk * hf[6], hk * hf[7]);
            bf16x8 bfb = *(const bf16x8*)(bRd + c * 512);
            acc = __builtin_amdgcn_mfma_f32_16x16x32_bf16(
                u4_as_bf16x8(a0, a1, a2, a3), bfb, acc, 0, 0, 0);
        }
        if (r0 + 0 < n_edge) atomicAdd(out + (size_t)nd.x * 16 + col, acc[0]);
        if (r0 + 1 < n_edge) atomicAdd(out + (size_t)nd.y * 16 + col, acc[1]);
        if (r0 + 2 < n_edge) atomicAdd(out + (size_t)nd.z * 16 + col, acc[2]);
        if (r0 + 3 < n_edge) atomicAdd(out + (size_t)nd.w * 16 + col, acc[3]);
    }
}

// out[i] = sum over the 8 per-XCD replicas. 51.2MB read + 6.4MB write (~15us).
__global__ void merge_rep(const fvec4* __restrict__ rep,
                          fvec4* __restrict__ out, int n4, int stride4)
{
    int i = blockIdx.x * blockDim.x + threadIdx.x;
    if (i >= n4) return;
    fvec4 s = rep[i];
    #pragma unroll
    for (int r = 1; r < NREP; r++)
        s += rep[(size_t)r * stride4 + i];
    out[i] = s;
}

extern "C" void kernel_launch(void* const* d_in, const int* in_sizes, int n_in,
                              void* d_out, int out_size, void* d_ws, size_t ws_size,
                              hipStream_t stream) {
    const int*   idx  = (const int*)  d_in[0];
    const float* h_w  = (const float*)d_in[1];
    const float* e_vw = (const float*)d_in[2];
    const float* W1   = (const float*)d_in[4];
    const float* b1   = (const float*)d_in[5];
    const float* W2   = (const float*)d_in[6];
    const float* b2   = (const float*)d_in[7];
    float* out = (float*)d_out;
    const int n_edge = in_sizes[0];

    const size_t out_floats = (size_t)out_size;           // n_node * 16
    const size_t need = (size_t)NREP * out_floats * sizeof(float);

    if (ws_size >= need && (out_floats & 3) == 0) {
        float* rep = (float*)d_ws;
        hipMemsetAsync(rep, 0, need, stream);
        msg_mfma32<<<1024, 512, 0, stream>>>(idx, h_w, e_vw, W1, b1, W2, b2,
                                             rep, n_edge, (int)out_floats);
        const int n4 = (int)(out_floats >> 2);
        const int mblocks = (n4 + 255) / 256;
        merge_rep<<<mblocks, 256, 0, stream>>>((const fvec4*)rep, (fvec4*)out,
                                               n4, n4);
    } else {
        hipMemsetAsync(out, 0, out_floats * sizeof(float), stream);
        msg_mfma_legacy<<<1536, 512, 0, stream>>>(idx, h_w, e_vw, W1, b1, W2,
                                                  b2, out, n_edge);
    }
}

// Round 9
// 314.450 us; speedup vs baseline: 2.0856x; 1.0195x over previous
//
#include <hip/hip_runtime.h>
#include <stdint.h>

typedef __bf16 bf16x8 __attribute__((ext_vector_type(8)));
typedef float  f32x4  __attribute__((ext_vector_type(4)));
typedef float  fvec4  __attribute__((ext_vector_type(4)));
typedef float  f32x2  __attribute__((ext_vector_type(2)));
typedef int    i32x4  __attribute__((ext_vector_type(4)));

#define EDIM   16
#define HIDDEN 64
#define MDIM   16
#define NDIM   16
// Big GEMM: K' = 64 hid rows x 16 n = 32 chunks of 32; bias row handled
// by one extra register-sourced MFMA per edge-group (A = h, B = b2 frag).
#define KCHUNKS 32
#define NREP   8   // one output replica per XCD
#define WPB    8   // waves per block (512 threads)

// truncating f32->bf16 pack of two floats into one dword (x in low half).
__device__ __forceinline__ uint32_t pack_trunc(float x, float y) {
    return __builtin_amdgcn_perm(__builtin_bit_cast(uint32_t, x),
                                 __builtin_bit_cast(uint32_t, y),
                                 0x03020706u);
}

__device__ __forceinline__ uint16_t f32_to_bf16_rne(float f) {
    uint32_t u = __builtin_bit_cast(uint32_t, f);
    u += 0x7FFFu + ((u >> 16) & 1u);
    return (uint16_t)(u >> 16);
}

__device__ __forceinline__ bf16x8 u4_as_bf16x8(uint32_t a, uint32_t b,
                                               uint32_t c, uint32_t d) {
    union { uint32_t u[4]; bf16x8 v; } x;
    x.u[0] = a; x.u[1] = b; x.u[2] = c; x.u[3] = d;
    return x.v;
}

// packed f32 multiply with src0.lo broadcast (VOP3P op_sel):
//   d.lo = a.lo * b.lo ; d.hi = a.lo * b.hi
// -> scalar-times-pair in ONE instruction, no {s,s} pair-build mov.
__device__ __forceinline__ f32x2 pk_mul_bcast(f32x2 a, f32x2 b) {
    f32x2 d;
    asm("v_pk_mul_f32 %0, %1, %2 op_sel_hi:[0,1]" : "=v"(d) : "v"(a), "v"(b));
    return d;
}

// L2-local fp32 atomic add, saddr form: 32-bit byte voffset + SGPR base.
// No sc0/sc1 bits -> RMW executes in the issuing XCD's TCC and the line
// stays dirty-resident there (no fabric round-trip).
__device__ __forceinline__ void atomic_add_s(const float* base, uint32_t off,
                                             float v) {
    asm volatile("global_atomic_add_f32 %0, %1, %2"
                 :: "v"(off), "v"(v), "s"(base) : "memory");
}

__device__ __forceinline__ void load_eh(const float* p, uint32_t ro,
                                        fvec4& a, fvec4& b) {
    const fvec4* pp = (const fvec4*)(p + ro);
    a = __builtin_nontemporal_load(pp);
    b = __builtin_nontemporal_load(pp + 1);
}

__device__ __forceinline__ i32x4 load_idx4(const int* __restrict__ idx,
                                           int r, int n_edge, bool full) {
    i32x4 v;
    if (full) {
        // r = tile_base + q*4 -> 16B aligned: one dwordx4
        v = __builtin_nontemporal_load((const i32x4*)(idx + r));
    } else {
        v.x = __builtin_nontemporal_load(idx + min(r + 0, n_edge - 1));
        v.y = __builtin_nontemporal_load(idx + min(r + 1, n_edge - 1));
        v.z = __builtin_nontemporal_load(idx + min(r + 2, n_edge - 1));
        v.w = __builtin_nontemporal_load(idx + min(r + 3, n_edge - 1));
    }
    return v;
}

// hid stage for one 16-edge group: 4 MFMAs, relu, pack, LDS transpose write.
__device__ __forceinline__ void hid_stage(fvec4 ea, fvec4 eb, int q,
                                          const bf16x8* w1f, ushort* hidWr) {
    uint32_t au0 = pack_trunc(ea.x, ea.y);
    uint32_t au1 = pack_trunc(ea.z, ea.w);
    uint32_t au2 = pack_trunc(eb.x, eb.y);
    uint32_t au3 = pack_trunc(eb.z, eb.w);
    if (q == 2) { au0 = 0x00003F80u; au1 = au2 = au3 = 0; } // bias row k=16 -> 1.0
    else if (q == 3) { au0 = au1 = au2 = au3 = 0; }
    bf16x8 av = u4_as_bf16x8(au0, au1, au2, au3);
    #pragma unroll
    for (int nt = 0; nt < 4; nt++) {
        f32x4 hc = {0.f, 0.f, 0.f, 0.f};
        hc = __builtin_amdgcn_mfma_f32_16x16x32_bf16(av, w1f[nt], hc, 0, 0, 0);
        // C layout: value = hid[e = q*4 + i][n = nt*16 + col]
        uint32_t lo = pack_trunc(fmaxf(hc[0], 0.f), fmaxf(hc[1], 0.f));
        uint32_t hi = pack_trunc(fmaxf(hc[2], 0.f), fmaxf(hc[3], 0.f));
        *(uint2*)(hidWr + nt * 256) = make_uint2(lo, hi); // sHid[k=nt*16+col][e=q*4..+3]
    }
}

// Per 32-edge tile (one wave, TWO 16-edge groups sharing each B-fragment):
//   hid-GEMM x2: A = [e|1|0..] (16x32), B = W1ext (32x64) -> hid, relu
//   big GEMM:  per chunk c: ONE ds_read_b128 of W2' feeds TWO MFMAs
//              (group0 and group1 A-frags) -> sB traffic per edge HALVED.
//   + 2 bias MFMAs (A = h, B = b2 fragment, register-sourced).
// LDS = 32KB sB + 32KB sHid = 64KB -> 2 blocks/CU. PERSISTENT grid: 512
// blocks = exactly 2/CU, one W2-staging per block lifetime, no dispatch
// churn (round 6 measured occupancy 34% of the 50% cap with grid 1024).
// Scatter: per-XCD replica (HW_REG_XCC_ID) + L2-local atomics; merge kernel
// sums the 8 replicas. In-place next-tile prefetch keeps all loads issued
// BEFORE this tile's atomics so in-order vmcnt never waits on atomics.
__global__ __launch_bounds__(512, 4) void msg_mfma32(
    const int*   __restrict__ idx,
    const float* __restrict__ h_w,
    const float* __restrict__ e_vw,
    const float* __restrict__ W1,   // [16][64]
    const float* __restrict__ b1,   // [64]
    const float* __restrict__ W2,   // [64][256]  ([k][m*16+n])
    const float* __restrict__ b2,   // [256]      ([m*16+n])
    float*       __restrict__ outb, // [NREP][n_node*16] pre-zeroed
    int n_edge, int rep_stride)
{
    // B-fragment-ordered W2: sB[c][q][m][j] = W2[k=2c+(q>>1)][m*16 + (q&1)*8+j]
    __align__(16) __shared__ ushort sB[KCHUNKS * 512];       // 32768 B
    // per-wave-per-group hid transpose: sHid[(w*2+g)][k][e], k = 0..63
    __align__(16) __shared__ ushort sHid[WPB * 2 * 1024];    // 32768 B

    const int tid = threadIdx.x;

    // ---- pick output replica (one per XCD) ----
    // s_getreg_b32 imm = ((size-1)<<11)|(offset<<6)|id ; HW_REG_XCC_ID = 20,
    // offset 0, size 4  ->  (3<<11)|20 = 6164.  Returns 0..7 on MI355X (m09).
    const int xcd = __builtin_amdgcn_s_getreg(6164) & (NREP - 1);
    const float* out = outb + (size_t)xcd * (size_t)rep_stride;

    // ---- stage W2 fragments (once per block) ----
    for (int t = tid; t < KCHUNKS * 512; t += 512) {
        int c = t >> 9, r = t & 511;
        int qq = r >> 7, m = (r >> 3) & 15, j = r & 7;
        int k = 2 * c + (qq >> 1);                     // 0..63
        int n = ((qq & 1) << 3) + j;
        sB[t] = f32_to_bf16_rne(W2[k * 256 + m * 16 + n]);
    }

    const int lane = tid & 63;
    const int q    = lane >> 4;    // quad-row 0..3
    const int col  = lane & 15;
    const int w    = tid >> 6;     // wave in block (0..7)

    // ---- W1ext B-fragments in registers (once per wave) ----
    uint32_t w1u[4][4];
    #pragma unroll
    for (int nt = 0; nt < 4; nt++) {
        #pragma unroll
        for (int d = 0; d < 4; d++) w1u[nt][d] = 0;
        #pragma unroll
        for (int j = 0; j < 8; j++) {
            int k = q * 8 + j;
            float v = 0.f;
            if (k < 16)       v = W1[k * 64 + nt * 16 + col];
            else if (k == 16) v = b1[nt * 16 + col];
            w1u[nt][j >> 1] |= ((uint32_t)f32_to_bf16_rne(v)) << ((j & 1) * 16);
        }
    }

    // ---- b2 B-fragment (bias MFMA): q<2 -> b2, q>=2 -> 0 ----
    uint32_t b2u[4] = {0, 0, 0, 0};
    if (q < 2) {
        const float* bp = b2 + col * 16 + q * 8;
        #pragma unroll
        for (int j = 0; j < 8; j++)
            b2u[j >> 1] |= ((uint32_t)f32_to_bf16_rne(bp[j])) << ((j & 1) * 16);
    }
    __syncthreads();

    bf16x8 w1f[4];
    #pragma unroll
    for (int nt = 0; nt < 4; nt++)
        w1f[nt] = u4_as_bf16x8(w1u[nt][0], w1u[nt][1], w1u[nt][2], w1u[nt][3]);
    const bf16x8 b2f = u4_as_bf16x8(b2u[0], b2u[1], b2u[2], b2u[3]);

    const int nhalf = (q & 1) << 3;  // which 8 of the 16 dims this quad holds
    const int ntile = (n_edge + 31) >> 5;       // 32 edges per tile
    const int wave_id = blockIdx.x * WPB + w;
    const int wstride = gridDim.x * WPB;
    if (wave_id >= ntile) return;

    const ushort* hidRd0 = &sHid[(w * 2 + 0) * 1024 + (q >> 1) * 16 + col];
    const ushort* hidRd1 = hidRd0 + 1024;
    ushort*       hidWr0 = &sHid[(w * 2 + 0) * 1024 + col * 16 + q * 4];
    ushort*       hidWr1 = hidWr0 + 1024;
    const ushort* bRd    = &sB[q * 128 + col * 8];            // + c*512
    const uint32_t col4  = (uint32_t)col * 4u;

    // ---- initial tile load ----
    int t = wave_id;
    fvec4 e0, e1, e2, e3, h0, h1, h2, h3; i32x4 nd0, nd1; bool full;
    {
        int rbase = t * 32;
        full = (rbase + 32 <= n_edge);
        int row0 = full ? (rbase + col)      : min(rbase + col,      n_edge - 1);
        int row1 = full ? (rbase + 16 + col) : min(rbase + 16 + col, n_edge - 1);
        uint32_t ro0 = (uint32_t)row0 * 16u + (uint32_t)nhalf;
        uint32_t ro1 = (uint32_t)row1 * 16u + (uint32_t)nhalf;
        load_eh(e_vw, ro0, e0, e1);
        load_eh(e_vw, ro1, e2, e3);
        load_eh(h_w,  ro0, h0, h1);
        load_eh(h_w,  ro1, h2, h3);
        nd0 = load_idx4(idx, rbase + q * 4,      n_edge, full);
        nd1 = load_idx4(idx, rbase + 16 + q * 4, n_edge, full);
    }

    while (true) {
        int tn = t + wstride;
        bool have_next = (tn < ntile);

        // ---- hid stage: both groups (consumes e0..e3) ----
        hid_stage(e0, e1, q, w1f, hidWr0);
        hid_stage(e2, e3, q, w1f, hidWr1);

        // ---- e-prefetch next tile, in place (e dead after hid stage);
        //      issues BEFORE this tile's atomics ----
        bool nfull = false;
        if (have_next) {
            int rbase = tn * 32;
            nfull = (rbase + 32 <= n_edge);
            int row0 = nfull ? (rbase + col)      : min(rbase + col,      n_edge - 1);
            int row1 = nfull ? (rbase + 16 + col) : min(rbase + 16 + col, n_edge - 1);
            load_eh(e_vw, (uint32_t)row0 * 16u + (uint32_t)nhalf, e0, e1);
            load_eh(e_vw, (uint32_t)row1 * 16u + (uint32_t)nhalf, e2, e3);
        }

        // h as packed f32 pairs for v_pk_mul_f32
        f32x2 hp0; hp0.x = h0.x; hp0.y = h0.y;
        f32x2 hp1; hp1.x = h0.z; hp1.y = h0.w;
        f32x2 hp2; hp2.x = h1.x; hp2.y = h1.y;
        f32x2 hp3; hp3.x = h1.z; hp3.y = h1.w;
        f32x2 hq0; hq0.x = h2.x; hq0.y = h2.y;
        f32x2 hq1; hq1.x = h2.z; hq1.y = h2.w;
        f32x2 hq2; hq2.x = h3.x; hq2.y = h3.y;
        f32x2 hq3; hq3.x = h3.z; hq3.y = h3.w;

        // ---- bias MFMAs (no dependency on the LDS hid round-trip) ----
        f32x4 acc0 = {0.f, 0.f, 0.f, 0.f};
        f32x4 acc1 = {0.f, 0.f, 0.f, 0.f};
        {
            bf16x8 af0 = u4_as_bf16x8(pack_trunc(hp0.x, hp0.y), pack_trunc(hp1.x, hp1.y),
                                      pack_trunc(hp2.x, hp2.y), pack_trunc(hp3.x, hp3.y));
            acc0 = __builtin_amdgcn_mfma_f32_16x16x32_bf16(af0, b2f, acc0, 0, 0, 0);
            bf16x8 af1 = u4_as_bf16x8(pack_trunc(hq0.x, hq0.y), pack_trunc(hq1.x, hq1.y),
                                      pack_trunc(hq2.x, hq2.y), pack_trunc(hq3.x, hq3.y));
            acc1 = __builtin_amdgcn_mfma_f32_16x16x32_bf16(af1, b2f, acc1, 0, 0, 0);
        }

        // ---- big GEMM: 32 chunks; ONE b128 B-read feeds TWO MFMAs.
        // hk pairs: only the lo half is live (op_sel broadcast); hi halves
        // initialized once so the pair register stays loop-invariant. ----
        f32x2 hkA = {0.f, 0.f}, hkB = {0.f, 0.f};
        #pragma unroll
        for (int c = 0; c < KCHUNKS; c++) {
            bf16x8 bfb = *(const bf16x8*)(bRd + c * 512);       // ds_read_b128
            // group 0
            {
                hkA[0] = __builtin_bit_cast(float,
                             ((uint32_t)hidRd0[c * 32]) << 16); // hid[k][e=col]
                f32x2 p0 = pk_mul_bcast(hkA, hp0);
                f32x2 p1 = pk_mul_bcast(hkA, hp1);
                f32x2 p2 = pk_mul_bcast(hkA, hp2);
                f32x2 p3 = pk_mul_bcast(hkA, hp3);
                bf16x8 af = u4_as_bf16x8(pack_trunc(p0.x, p0.y), pack_trunc(p1.x, p1.y),
                                         pack_trunc(p2.x, p2.y), pack_trunc(p3.x, p3.y));
                acc0 = __builtin_amdgcn_mfma_f32_16x16x32_bf16(af, bfb, acc0, 0, 0, 0);
            }
            // group 1 (reuses bfb)
            {
                hkB[0] = __builtin_bit_cast(float,
                             ((uint32_t)hidRd1[c * 32]) << 16);
                f32x2 p0 = pk_mul_bcast(hkB, hq0);
                f32x2 p1 = pk_mul_bcast(hkB, hq1);
                f32x2 p2 = pk_mul_bcast(hkB, hq2);
                f32x2 p3 = pk_mul_bcast(hkB, hq3);
                bf16x8 af = u4_as_bf16x8(pack_trunc(p0.x, p0.y), pack_trunc(p1.x, p1.y),
                                         pack_trunc(p2.x, p2.y), pack_trunc(p3.x, p3.y));
                acc1 = __builtin_amdgcn_mfma_f32_16x16x32_bf16(af, bfb, acc1, 0, 0, 0);
            }
        }

        // ---- h + nd prefetch next (h in place: dead after chunk loop);
        //      still issues BEFORE this tile's atomics ----
        i32x4 ndn0, ndn1;
        if (have_next) {
            int rbase = tn * 32;
            int row0 = nfull ? (rbase + col)      : min(rbase + col,      n_edge - 1);
            int row1 = nfull ? (rbase + 16 + col) : min(rbase + 16 + col, n_edge - 1);
            load_eh(h_w, (uint32_t)row0 * 16u + (uint32_t)nhalf, h0, h1);
            load_eh(h_w, (uint32_t)row1 * 16u + (uint32_t)nhalf, h2, h3);
            ndn0 = load_idx4(idx, rbase + q * 4,      n_edge, nfull);
            ndn1 = load_idx4(idx, rbase + 16 + q * 4, n_edge, nfull);
        }

        // ---- epilogue: L2-local atomics (replica is single-XCD-writer) ----
        if (full) {
            atomic_add_s(out, (uint32_t)nd0.x * 64u + col4, acc0[0]);
            atomic_add_s(out, (uint32_t)nd0.y * 64u + col4, acc0[1]);
            atomic_add_s(out, (uint32_t)nd0.z * 64u + col4, acc0[2]);
            atomic_add_s(out, (uint32_t)nd0.w * 64u + col4, acc0[3]);
            atomic_add_s(out, (uint32_t)nd1.x * 64u + col4, acc1[0]);
            atomic_add_s(out, (uint32_t)nd1.y * 64u + col4, acc1[1]);
            atomic_add_s(out, (uint32_t)nd1.z * 64u + col4, acc1[2]);
            atomic_add_s(out, (uint32_t)nd1.w * 64u + col4, acc1[3]);
        } else {
            int r0 = t * 32 + q * 4;
            int r1 = r0 + 16;
            if (r0 + 0 < n_edge) atomic_add_s(out, (uint32_t)nd0.x * 64u + col4, acc0[0]);
            if (r0 + 1 < n_edge) atomic_add_s(out, (uint32_t)nd0.y * 64u + col4, acc0[1]);
            if (r0 + 2 < n_edge) atomic_add_s(out, (uint32_t)nd0.z * 64u + col4, acc0[2]);
            if (r0 + 3 < n_edge) atomic_add_s(out, (uint32_t)nd0.w * 64u + col4, acc0[3]);
            if (r1 + 0 < n_edge) atomic_add_s(out, (uint32_t)nd1.x * 64u + col4, acc1[0]);
            if (r1 + 1 < n_edge) atomic_add_s(out, (uint32_t)nd1.y * 64u + col4, acc1[1]);
            if (r1 + 2 < n_edge) atomic_add_s(out, (uint32_t)nd1.z * 64u + col4, acc1[2]);
            if (r1 + 3 < n_edge) atomic_add_s(out, (uint32_t)nd1.w * 64u + col4, acc1[3]);
        }

        if (!have_next) break;
        t = tn; full = nfull; nd0 = ndn0; nd1 = ndn1;
    }
}

// ---- legacy fallback (ws too small): 16-edge kernel, device atomics ----
__global__ __launch_bounds__(512, 6) void msg_mfma_legacy(
    const int*   __restrict__ idx,
    const float* __restrict__ h_w,
    const float* __restrict__ e_vw,
    const float* __restrict__ W1,
    const float* __restrict__ b1,
    const float* __restrict__ W2,
    const float* __restrict__ b2,
    float*       __restrict__ out,
    int n_edge)
{
    __align__(16) __shared__ ushort sB[KCHUNKS * 512];
    __align__(16) __shared__ ushort sHid[WPB * 64 * 16];
    const int tid = threadIdx.x;
    for (int t = tid; t < KCHUNKS * 512; t += 512) {
        int c = t >> 9, r = t & 511;
        int qq = r >> 7, m = (r >> 3) & 15, j = r & 7;
        int k = 2 * c + (qq >> 1);
        int n = ((qq & 1) << 3) + j;
        sB[t] = f32_to_bf16_rne(W2[k * 256 + m * 16 + n]);
    }
    const int lane = tid & 63, q = lane >> 4, col = lane & 15, w = tid >> 6;
    uint32_t w1u[4][4];
    #pragma unroll
    for (int nt = 0; nt < 4; nt++) {
        #pragma unroll
        for (int d = 0; d < 4; d++) w1u[nt][d] = 0;
        #pragma unroll
        for (int j = 0; j < 8; j++) {
            int k = q * 8 + j;
            float v = 0.f;
            if (k < 16)       v = W1[k * 64 + nt * 16 + col];
            else if (k == 16) v = b1[nt * 16 + col];
            w1u[nt][j >> 1] |= ((uint32_t)f32_to_bf16_rne(v)) << ((j & 1) * 16);
        }
    }
    uint32_t b2u[4] = {0, 0, 0, 0};
    if (q < 2) {
        const float* bp = b2 + col * 16 + q * 8;
        #pragma unroll
        for (int j = 0; j < 8; j++)
            b2u[j >> 1] |= ((uint32_t)f32_to_bf16_rne(bp[j])) << ((j & 1) * 16);
    }
    __syncthreads();
    bf16x8 w1f[4];
    #pragma unroll
    for (int nt = 0; nt < 4; nt++)
        w1f[nt] = u4_as_bf16x8(w1u[nt][0], w1u[nt][1], w1u[nt][2], w1u[nt][3]);
    const bf16x8 b2f = u4_as_bf16x8(b2u[0], b2u[1], b2u[2], b2u[3]);
    const int nhalf = (q & 1) << 3;
    const int ntile = (n_edge + 15) >> 4;
    int t = blockIdx.x * WPB + w;
    const int wstride = gridDim.x * WPB;
    const ushort* hidRd = &sHid[w * 1024 + (q >> 1) * 16 + col];
    ushort*       hidWr = &sHid[w * 1024 + col * 16 + q * 4];
    const ushort* bRd   = &sB[q * 128 + col * 8];
    for (; t < ntile; t += wstride) {
        int row = min(t * 16 + col, n_edge - 1);
        const fvec4* ep = (const fvec4*)(e_vw + (size_t)row * 16 + nhalf);
        fvec4 e0 = ep[0], e1 = ep[1];
        const fvec4* hpp = (const fvec4*)(h_w + (size_t)row * 16 + nhalf);
        fvec4 h0 = hpp[0], h1 = hpp[1];
        int r0 = t * 16 + q * 4;
        int4 nd;
        nd.x = idx[min(r0 + 0, n_edge - 1)];
        nd.y = idx[min(r0 + 1, n_edge - 1)];
        nd.z = idx[min(r0 + 2, n_edge - 1)];
        nd.w = idx[min(r0 + 3, n_edge - 1)];
        hid_stage(e0, e1, q, w1f, hidWr);
        float hf[8] = {h0.x, h0.y, h0.z, h0.w, h1.x, h1.y, h1.z, h1.w};
        f32x4 acc = {0.f, 0.f, 0.f, 0.f};
        {
            uint32_t a0 = pack_trunc(hf[0], hf[1]);
            uint32_t a1 = pack_trunc(hf[2], hf[3]);
            uint32_t a2 = pack_trunc(hf[4], hf[5]);
            uint32_t a3 = pack_trunc(hf[6], hf[7]);
            acc = __builtin_amdgcn_mfma_f32_16x16x32_bf16(
                u4_as_bf16x8(a0, a1, a2, a3), b2f, acc, 0, 0, 0);
        }
        #pragma unroll
        for (int c = 0; c < KCHUNKS; c++) {
            uint32_t hku = ((uint32_t)hidRd[c * 32]) << 16;
            float hk = __builtin_bit_cast(float, hku);
            uint32_t a0 = pack_trunc(hk * hf[0], hk * hf[1]);
            uint32_t a1 = pack_trunc(hk * hf[2], hk * hf[3]);
            uint32_t a2 = pack_trunc(hk * hf[4], hk * hf[5]);
            uint32_t a3 = pack_trunc(hk * hf[6], hk * hf[7]);
            bf16x8 bfb = *(const bf16x8*)(bRd + c * 512);
            acc = __builtin_amdgcn_mfma_f32_16x16x32_bf16(
                u4_as_bf16x8(a0, a1, a2, a3), bfb, acc, 0, 0, 0);
        }
        if (r0 + 0 < n_edge) atomicAdd(out + (size_t)nd.x * 16 + col, acc[0]);
        if (r0 + 1 < n_edge) atomicAdd(out + (size_t)nd.y * 16 + col, acc[1]);
        if (r0 + 2 < n_edge) atomicAdd(out + (size_t)nd.z * 16 + col, acc[2]);
        if (r0 + 3 < n_edge) atomicAdd(out + (size_t)nd.w * 16 + col, acc[3]);
    }
}

// out[i] = sum over the 8 per-XCD replicas. 51.2MB read + 6.4MB write (~15us).
__global__ void merge_rep(const fvec4* __restrict__ rep,
                          fvec4* __restrict__ out, int n4, int stride4)
{
    int i = blockIdx.x * blockDim.x + threadIdx.x;
    if (i >= n4) return;
    fvec4 s = rep[i];
    #pragma unroll
    for (int r = 1; r < NREP; r++)
        s += rep[(size_t)r * stride4 + i];
    out[i] = s;
}

extern "C" void kernel_launch(void* const* d_in, const int* in_sizes, int n_in,
                              void* d_out, int out_size, void* d_ws, size_t ws_size,
                              hipStream_t stream) {
    const int*   idx  = (const int*)  d_in[0];
    const float* h_w  = (const float*)d_in[1];
    const float* e_vw = (const float*)d_in[2];
    const float* W1   = (const float*)d_in[4];
    const float* b1   = (const float*)d_in[5];
    const float* W2   = (const float*)d_in[6];
    const float* b2   = (const float*)d_in[7];
    float* out = (float*)d_out;
    const int n_edge = in_sizes[0];

    const size_t out_floats = (size_t)out_size;           // n_node * 16
    const size_t need = (size_t)NREP * out_floats * sizeof(float);

    if (ws_size >= need && (out_floats & 3) == 0) {
        float* rep = (float*)d_ws;
        (void)hipMemsetAsync(rep, 0, need, stream);
        // persistent grid: 512 blocks = exactly 2 resident blocks per CU
        msg_mfma32<<<512, 512, 0, stream>>>(idx, h_w, e_vw, W1, b1, W2, b2,
                                            rep, n_edge, (int)out_floats);
        const int n4 = (int)(out_floats >> 2);
        const int mblocks = (n4 + 255) / 256;
        merge_rep<<<mblocks, 256, 0, stream>>>((const fvec4*)rep, (fvec4*)out,
                                               n4, n4);
    } else {
        (void)hipMemsetAsync(out, 0, out_floats * sizeof(float), stream);
        msg_mfma_legacy<<<1536, 512, 0, stream>>>(idx, h_w, e_vw, W1, b1, W2,
                                                  b2, out, n_edge);
    }
}